// Round 11
// baseline (103.951 us; speedup 1.0000x reference)
//
#include <hip/hip_runtime.h>
#include <utility>

// ConvQuad2D as ONE pure GEMM over packed-f16 pair-features.
// r10 post-mortem: main kernel is LDS-unit-throughput-bound (per-CU pipe):
// per 32-pix wave: B 49 ds_read_b128 (588cyc) + patch 50 ds_read_b32 (290) +
// writes ~100 => ~950 LDS cyc/wave x 61 waves/CU ~= 24us/CU — swapping B
// between global and LDS was an even trade (r10 gained only 3us).
// r11: 64 pixels/wave (4 segments, 64x8 tile/block) — waves halve, so B's
// 50KB/wave LDS traffic per pixel halves: DS/CU ~39k cyc (~16us). Patch/VALU
// totals unchanged. LDS = 13KB x-tile + 50KB B = 63.2KB -> 2 blocks/CU = 4
// waves/SIMD, launch_bounds(512,4) caps VGPR at 128 (pd 52 + acc 16 + tmp).
// Feature order (prep owns matching weights): slot s in [0,196):
//   s<181: pair (i,g), g in [i>>1,12]: (p_i*p_{2g}, p_i*p_{2g+1});
//          weights: j==i -> Wq[d,i,i]; j>i -> Wq[d,i,j]+Wq[d,j,i]; else 0
//   s<194: linear t=s-181: (p_{2t},p_{2t+1}) w/ Klin[j,d,o] (j==25 -> 0); else pad.
// k-slot: chunk c=s>>2, lane q = channel d, e = feature-in-chunk.

typedef _Float16 half2 __attribute__((ext_vector_type(2)));
typedef _Float16 half4 __attribute__((ext_vector_type(4)));
typedef _Float16 half8 __attribute__((ext_vector_type(8)));
typedef float floatx4 __attribute__((ext_vector_type(4)));

#define BB 8
#define HH 250
#define WW 250
#define NF 16
#define NSLOT_PAIR 181
#define NSLOT_LIN  13
#define NCHUNK     49              // 49*4 = 196 half2 slots = 392 features/channel
#define NFRAG      (NCHUNK * 64)   // 3136 B-fragments = 50,176 B

#define TW 64                 // tile width  (pixels) = 4 segments of 16
#define TH 8                  // tile height (= waves/block)
#define XW (TW + 4)           // 68 staged cols
#define XH (TH + 4)           // 12 staged rows
#define XSZ (XW * XH)         // 816 positions

__host__ __device__ constexpr int slot_i(int s) {
    int i = 0, base = 0;
    while (base + (13 - (i >> 1)) <= s) { base += 13 - (i >> 1); ++i; }
    return i;
}
__host__ __device__ constexpr int slot_g(int s) {
    int i = 0, base = 0;
    while (base + (13 - (i >> 1)) <= s) { base += 13 - (i >> 1); ++i; }
    return (i >> 1) + (s - base);
}

// ---------- pre-pass: B fragments in MFMA lane order ----------
__global__ void prep_frags(const float* __restrict__ lin_w,   // (5,5,4,16)
                           const float* __restrict__ quad_w,  // (4,25,25,16)
                           _Float16* __restrict__ fragB) {
    const int c = blockIdx.x;       // 0..48
    const int lane = threadIdx.x;   // 0..63
    const int n = lane & 15;
    const int d = lane >> 4;
    half8 frag;
    #pragma unroll
    for (int e = 0; e < 8; ++e) {
        const int f = c * 8 + e;
        const int s = f >> 1, hf = f & 1;
        float v = 0.f;
        if (s < NSLOT_PAIR) {
            int i = 0, base = 0;
            while (base + (13 - (i >> 1)) <= s) { base += 13 - (i >> 1); ++i; }
            const int g = (i >> 1) + (s - base);
            const int j = 2 * g + hf;
            if (j == i)
                v = quad_w[((d * 25 + i) * 25 + i) * 16 + n];
            else if (j > i && j < 25)
                v = quad_w[((d * 25 + i) * 25 + j) * 16 + n]
                  + quad_w[((d * 25 + j) * 25 + i) * 16 + n];
        } else if (s < NSLOT_PAIR + NSLOT_LIN) {
            const int j = 2 * (s - NSLOT_PAIR) + hf;
            if (j < 25) v = lin_w[(j * 4 + d) * 16 + n];
        }
        frag[e] = (_Float16)v;
    }
    *(half8*)(fragB + (c * 64 + lane) * 8) = frag;
}

// ---------- packed helpers ----------
__device__ __forceinline__ half2 pk(float lo, float hi) {
    return __builtin_bit_cast(half2, __builtin_amdgcn_cvt_pkrtz(lo, hi));
}

template<int S>
__device__ __forceinline__ half2 slotval(const half2 (&pd2)[13]) {
    if constexpr (S < NSLOT_PAIR) {
        constexpr int i = slot_i(S), g = slot_g(S);
        constexpr int ir = i >> 1, ih = i & 1;
        const half2 src = pd2[ir];
        const half2 bi = {src[ih], src[ih]};   // op_sel broadcast
        return bi * pd2[g];                    // v_pk_mul_f16
    } else if constexpr (S < NSLOT_PAIR + NSLOT_LIN) {
        return pd2[S - NSLOT_PAIR];
    } else {
        return half2{(_Float16)0.f, (_Float16)0.f};
    }
}

template<int C>
__device__ __forceinline__ half8 make_frag(const half2 (&pd2)[13]) {
    const half2 a0 = slotval<C * 4 + 0>(pd2);
    const half2 a1 = slotval<C * 4 + 1>(pd2);
    const half2 a2 = slotval<C * 4 + 2>(pd2);
    const half2 a3 = slotval<C * 4 + 3>(pd2);
    const half4 lo = __builtin_shufflevector(a0, a1, 0, 1, 2, 3);
    const half4 hi = __builtin_shufflevector(a2, a3, 0, 1, 2, 3);
    return __builtin_shufflevector(lo, hi, 0, 1, 2, 3, 4, 5, 6, 7);
}

template<size_t... Cs>
__device__ __forceinline__ void gemm_all(
    const half2 (&p0)[13], const half2 (&p1)[13],
    const half2 (&p2)[13], const half2 (&p3)[13],
    const _Float16* sBlane,
    floatx4& a0, floatx4& a1, floatx4& a2, floatx4& a3,
    std::index_sequence<Cs...>) {
    (([&] {
        constexpr int C = (int)Cs;
        const half8 bf = *(const half8*)(sBlane + C * 64 * 8);  // ds_read_b128 imm
        a0 = __builtin_amdgcn_mfma_f32_16x16x32_f16(make_frag<C>(p0), bf, a0, 0, 0, 0);
        a1 = __builtin_amdgcn_mfma_f32_16x16x32_f16(make_frag<C>(p1), bf, a1, 0, 0, 0);
        a2 = __builtin_amdgcn_mfma_f32_16x16x32_f16(make_frag<C>(p2), bf, a2, 0, 0, 0);
        a3 = __builtin_amdgcn_mfma_f32_16x16x32_f16(make_frag<C>(p3), bf, a3, 0, 0, 0);
    }()), ...);
}

// ---------- patch from LDS x-tile: 25 imm-offset ds_reads + 13 cvt ----------
__device__ __forceinline__ void patch_from_lds(const float* xt, int base,
                                               half2 (&pd2)[13]) {
    float pf[26];
    pf[25] = 0.f;
    #pragma unroll
    for (int kh = 0; kh < 5; ++kh)
        #pragma unroll
        for (int kw = 0; kw < 5; ++kw)
            pf[kh * 5 + kw] = xt[base + kh * XW + kw];
    #pragma unroll
    for (int t = 0; t < 13; ++t) pd2[t] = pk(pf[2 * t], pf[2 * t + 1]);
}

// ---------- main kernel: 512 thr = 8 waves; wave = 1 row x 64 cols ----------
__global__ __launch_bounds__(512, 4) void convquad_gemm(
    const float* __restrict__ x,       // (8,250,250,4)
    const float* __restrict__ bias,    // (16,)
    const _Float16* __restrict__ fragB,
    float* __restrict__ out)           // (8,250,250,16)
{
    __shared__ float xt[4 * XSZ];                     // 13,056 B: [c][hh][ww]
    __shared__ __align__(16) _Float16 sB[NFRAG * 8];  // 50,176 B

    const int w0 = blockIdx.x * TW;
    const int h0 = blockIdx.y * TH;
    const int b  = blockIdx.z;

    {   // coalesced 50KB B copy: global (L2-hot) -> LDS
        const float4* src = (const float4*)fragB;
        float4* dst = (float4*)sB;
        #pragma unroll
        for (int t = threadIdx.x; t < NFRAG * 8 / 8; t += 512) dst[t] = src[t];
    }

    // ---- stage haloed x-tile (borders zeroed -> no masks later) ----
    #pragma unroll 2
    for (int p = threadIdx.x; p < XSZ; p += 512) {
        const int hh = p / XW, ww = p % XW;
        const int r = h0 + hh - 2, c = w0 + ww - 2;
        float4 v = make_float4(0.f, 0.f, 0.f, 0.f);
        if ((unsigned)r < (unsigned)HH && (unsigned)c < (unsigned)WW)
            v = ((const float4*)x)[(b * HH + r) * WW + c];
        xt[0 * XSZ + p] = v.x;
        xt[1 * XSZ + p] = v.y;
        xt[2 * XSZ + p] = v.z;
        xt[3 * XSZ + p] = v.w;
    }
    __syncthreads();

    const int lane = threadIdx.x & 63;
    const int wave = threadIdx.x >> 6;   // row within tile
    const int m = lane & 15;             // pixel within 16-col segment; also o
    const int q = lane >> 4;             // channel for A; row-quad for D

    // four 16-col segments per wave (cols 0..63)
    const int base0 = q * XSZ + wave * XW + m;
    half2 pd0[13], pd1[13], pd2[13], pd3[13];
    patch_from_lds(xt, base0,      pd0);
    patch_from_lds(xt, base0 + 16, pd1);
    patch_from_lds(xt, base0 + 32, pd2);
    patch_from_lds(xt, base0 + 48, pd3);

    const float bo = bias[m];
    floatx4 acc0 = {bo, bo, bo, bo};
    floatx4 acc1 = acc0, acc2 = acc0, acc3 = acc0;

    gemm_all(pd0, pd1, pd2, pd3, sB + lane * 8,
             acc0, acc1, acc2, acc3, std::make_index_sequence<NCHUNK>{});

    // ---- store: pixel w-offset = seg*16 + q*4 + r, o = m ----
    const int h = h0 + wave;
    if (h < HH) {
        const int rowbase = (b * HH + h) * WW;
        #pragma unroll
        for (int r = 0; r < 4; ++r) {
            const int wA = w0 + q * 4 + r;
            if (wA < WW) out[(rowbase + wA) * NF + m] = acc0[r];
            const int wB = w0 + 16 + q * 4 + r;
            if (wB < WW) out[(rowbase + wB) * NF + m] = acc1[r];
            const int wC = w0 + 32 + q * 4 + r;
            if (wC < WW) out[(rowbase + wC) * NF + m] = acc2[r];
            const int wD = w0 + 48 + q * 4 + r;
            if (wD < WW) out[(rowbase + wD) * NF + m] = acc3[r];
        }
    }
}

extern "C" void kernel_launch(void* const* d_in, const int* in_sizes, int n_in,
                              void* d_out, int out_size, void* d_ws, size_t ws_size,
                              hipStream_t stream) {
    const float* x      = (const float*)d_in[0];
    const float* lin_w  = (const float*)d_in[1];
    const float* quad_w = (const float*)d_in[2];
    const float* bias   = (const float*)d_in[3];
    float* out = (float*)d_out;
    _Float16* fragB = (_Float16*)d_ws;   // 50,176 B

    prep_frags<<<dim3(NCHUNK), dim3(64), 0, stream>>>(lin_w, quad_w, fragB);

    dim3 grid((WW + TW - 1) / TW, (HH + TH - 1) / TH, BB);   // 4 x 32 x 8 = 1024
    convquad_gemm<<<grid, dim3(512), 0, stream>>>(x, bias, fragB, out);
}

// Round 12
// 102.407 us; speedup vs baseline: 1.0151x; 1.0151x over previous
//
#include <hip/hip_runtime.h>
#include <utility>

// ConvQuad2D as ONE pure GEMM over packed-f16 pair-features.
// r11 post-mortem: halving B-LDS traffic moved the wall 0us -> kernel is NOT
// issue-bound (issue floor ~16us/CU vs ~38us wall). Residual is block-level
// coupling: 1024 short blocks each serialize {50KB B-copy -> x-stage ->
// barrier} before any MFMA. r12: 512 PERSISTENT blocks (2/CU); B staged once
// per block; loop over 2 tiles with x-halo loads for tile t+1 issued into
// REGISTERS before compute of tile t (latency hidden behind ~1.1us compute),
// then a cheap regs->LDS write + barrier. Steady-state issue mix identical
// to r11; staging leaves the critical path.
// Feature order (prep owns matching weights): slot s in [0,196):
//   s<181: pair (i,g), g in [i>>1,12]: (p_i*p_{2g}, p_i*p_{2g+1});
//          weights: j==i -> Wq[d,i,i]; j>i -> Wq[d,i,j]+Wq[d,j,i]; else 0
//   s<194: linear t=s-181: (p_{2t},p_{2t+1}) w/ Klin[j,d,o] (j==25 -> 0); else pad.
// k-slot: chunk c=s>>2, lane q = channel d, e = feature-in-chunk.

typedef _Float16 half2 __attribute__((ext_vector_type(2)));
typedef _Float16 half4 __attribute__((ext_vector_type(4)));
typedef _Float16 half8 __attribute__((ext_vector_type(8)));
typedef float floatx4 __attribute__((ext_vector_type(4)));

#define BB 8
#define HH 250
#define WW 250
#define NF 16
#define NSLOT_PAIR 181
#define NSLOT_LIN  13
#define NCHUNK     49              // 49*4 = 196 half2 slots = 392 features/channel
#define NFRAG      (NCHUNK * 64)   // 3136 B-fragments = 50,176 B

#define TW 64                 // tile width  (pixels) = 4 segments of 16
#define TH 8                  // tile height (= waves/block)
#define XW (TW + 4)           // 68 staged cols
#define XH (TH + 4)           // 12 staged rows
#define XSZ (XW * XH)         // 816 positions

#define NBLK     512          // persistent blocks (2/CU)
#define NTILE_W  4            // ceil(250/64)
#define NTILE_H  32           // ceil(250/8)
#define NTILES   (BB * NTILE_H * NTILE_W)   // 1024
#define NT       (NTILES / NBLK)            // 2 tiles per block

__host__ __device__ constexpr int slot_i(int s) {
    int i = 0, base = 0;
    while (base + (13 - (i >> 1)) <= s) { base += 13 - (i >> 1); ++i; }
    return i;
}
__host__ __device__ constexpr int slot_g(int s) {
    int i = 0, base = 0;
    while (base + (13 - (i >> 1)) <= s) { base += 13 - (i >> 1); ++i; }
    return (i >> 1) + (s - base);
}

// ---------- pre-pass: B fragments in MFMA lane order ----------
__global__ void prep_frags(const float* __restrict__ lin_w,   // (5,5,4,16)
                           const float* __restrict__ quad_w,  // (4,25,25,16)
                           _Float16* __restrict__ fragB) {
    const int c = blockIdx.x;       // 0..48
    const int lane = threadIdx.x;   // 0..63
    const int n = lane & 15;
    const int d = lane >> 4;
    half8 frag;
    #pragma unroll
    for (int e = 0; e < 8; ++e) {
        const int f = c * 8 + e;
        const int s = f >> 1, hf = f & 1;
        float v = 0.f;
        if (s < NSLOT_PAIR) {
            int i = 0, base = 0;
            while (base + (13 - (i >> 1)) <= s) { base += 13 - (i >> 1); ++i; }
            const int g = (i >> 1) + (s - base);
            const int j = 2 * g + hf;
            if (j == i)
                v = quad_w[((d * 25 + i) * 25 + i) * 16 + n];
            else if (j > i && j < 25)
                v = quad_w[((d * 25 + i) * 25 + j) * 16 + n]
                  + quad_w[((d * 25 + j) * 25 + i) * 16 + n];
        } else if (s < NSLOT_PAIR + NSLOT_LIN) {
            const int j = 2 * (s - NSLOT_PAIR) + hf;
            if (j < 25) v = lin_w[(j * 4 + d) * 16 + n];
        }
        frag[e] = (_Float16)v;
    }
    *(half8*)(fragB + (c * 64 + lane) * 8) = frag;
}

// ---------- packed helpers ----------
__device__ __forceinline__ half2 pk(float lo, float hi) {
    return __builtin_bit_cast(half2, __builtin_amdgcn_cvt_pkrtz(lo, hi));
}

template<int S>
__device__ __forceinline__ half2 slotval(const half2 (&pd2)[13]) {
    if constexpr (S < NSLOT_PAIR) {
        constexpr int i = slot_i(S), g = slot_g(S);
        constexpr int ir = i >> 1, ih = i & 1;
        const half2 src = pd2[ir];
        const half2 bi = {src[ih], src[ih]};   // op_sel broadcast
        return bi * pd2[g];                    // v_pk_mul_f16
    } else if constexpr (S < NSLOT_PAIR + NSLOT_LIN) {
        return pd2[S - NSLOT_PAIR];
    } else {
        return half2{(_Float16)0.f, (_Float16)0.f};
    }
}

template<int C>
__device__ __forceinline__ half8 make_frag(const half2 (&pd2)[13]) {
    const half2 a0 = slotval<C * 4 + 0>(pd2);
    const half2 a1 = slotval<C * 4 + 1>(pd2);
    const half2 a2 = slotval<C * 4 + 2>(pd2);
    const half2 a3 = slotval<C * 4 + 3>(pd2);
    const half4 lo = __builtin_shufflevector(a0, a1, 0, 1, 2, 3);
    const half4 hi = __builtin_shufflevector(a2, a3, 0, 1, 2, 3);
    return __builtin_shufflevector(lo, hi, 0, 1, 2, 3, 4, 5, 6, 7);
}

template<size_t... Cs>
__device__ __forceinline__ void gemm_all(
    const half2 (&p0)[13], const half2 (&p1)[13],
    const half2 (&p2)[13], const half2 (&p3)[13],
    const _Float16* sBlane,
    floatx4& a0, floatx4& a1, floatx4& a2, floatx4& a3,
    std::index_sequence<Cs...>) {
    (([&] {
        constexpr int C = (int)Cs;
        const half8 bf = *(const half8*)(sBlane + C * 64 * 8);  // ds_read_b128 imm
        a0 = __builtin_amdgcn_mfma_f32_16x16x32_f16(make_frag<C>(p0), bf, a0, 0, 0, 0);
        a1 = __builtin_amdgcn_mfma_f32_16x16x32_f16(make_frag<C>(p1), bf, a1, 0, 0, 0);
        a2 = __builtin_amdgcn_mfma_f32_16x16x32_f16(make_frag<C>(p2), bf, a2, 0, 0, 0);
        a3 = __builtin_amdgcn_mfma_f32_16x16x32_f16(make_frag<C>(p3), bf, a3, 0, 0, 0);
    }()), ...);
}

// ---------- patch from LDS x-tile: 25 imm-offset ds_reads + 13 cvt ----------
__device__ __forceinline__ void patch_from_lds(const float* xt, int base,
                                               half2 (&pd2)[13]) {
    float pf[26];
    pf[25] = 0.f;
    #pragma unroll
    for (int kh = 0; kh < 5; ++kh)
        #pragma unroll
        for (int kw = 0; kw < 5; ++kw)
            pf[kh * 5 + kw] = xt[base + kh * XW + kw];
    #pragma unroll
    for (int t = 0; t < 13; ++t) pd2[t] = pk(pf[2 * t], pf[2 * t + 1]);
}

// ---------- tile index -> (b, h0, w0) ----------
__device__ __forceinline__ void tile_coords(int T, int& b, int& h0, int& w0) {
    b = T >> 7;                  // 128 tiles per batch image
    const int rem = T & 127;
    h0 = (rem >> 2) * TH;
    w0 = (rem & 3) * TW;
}

// ---------- x-halo prefetch into registers (2 positions/thread) ----------
__device__ __forceinline__ void xload_regs(const float* __restrict__ x,
                                           int b, int h0, int w0,
                                           float4& v0, float4& v1) {
    const int p0 = threadIdx.x;
    {
        const int hh = p0 / XW, ww = p0 % XW;
        const int r = h0 + hh - 2, c = w0 + ww - 2;
        v0 = make_float4(0.f, 0.f, 0.f, 0.f);
        if ((unsigned)r < (unsigned)HH && (unsigned)c < (unsigned)WW)
            v0 = ((const float4*)x)[(b * HH + r) * WW + c];
    }
    const int p1 = p0 + 512;
    v1 = make_float4(0.f, 0.f, 0.f, 0.f);
    if (p1 < XSZ) {
        const int hh = p1 / XW, ww = p1 % XW;
        const int r = h0 + hh - 2, c = w0 + ww - 2;
        if ((unsigned)r < (unsigned)HH && (unsigned)c < (unsigned)WW)
            v1 = ((const float4*)x)[(b * HH + r) * WW + c];
    }
}

__device__ __forceinline__ void xwrite_lds(float* xt, const float4& v0, const float4& v1) {
    const int p0 = threadIdx.x;
    xt[0 * XSZ + p0] = v0.x;
    xt[1 * XSZ + p0] = v0.y;
    xt[2 * XSZ + p0] = v0.z;
    xt[3 * XSZ + p0] = v0.w;
    const int p1 = p0 + 512;
    if (p1 < XSZ) {
        xt[0 * XSZ + p1] = v1.x;
        xt[1 * XSZ + p1] = v1.y;
        xt[2 * XSZ + p1] = v1.z;
        xt[3 * XSZ + p1] = v1.w;
    }
}

// ---------- main kernel: 512 persistent threads, 2 tiles per block ----------
__global__ __launch_bounds__(512, 4) void convquad_gemm(
    const float* __restrict__ x,       // (8,250,250,4)
    const float* __restrict__ bias,    // (16,)
    const _Float16* __restrict__ fragB,
    float* __restrict__ out)           // (8,250,250,16)
{
    __shared__ float xt[4 * XSZ];                     // 13,056 B: [c][hh][ww]
    __shared__ __align__(16) _Float16 sB[NFRAG * 8];  // 50,176 B

    const int lane = threadIdx.x & 63;
    const int wave = threadIdx.x >> 6;   // row within tile
    const int m = lane & 15;             // pixel within 16-col segment; also o
    const int q = lane >> 4;             // channel for A; row-quad for D
    const float bo = bias[m];

    // ---- prologue: prefetch x (tile 0) + copy B, one barrier ----
    int b, h0, w0;
    tile_coords(blockIdx.x, b, h0, w0);
    float4 v0, v1;
    xload_regs(x, b, h0, w0, v0, v1);

    {   // coalesced 50KB B copy: global (L2-hot) -> LDS
        const float4* src = (const float4*)fragB;
        float4* dst = (float4*)sB;
        #pragma unroll
        for (int t = threadIdx.x; t < NFRAG * 8 / 8; t += 512) dst[t] = src[t];
    }
    xwrite_lds(xt, v0, v1);
    __syncthreads();

    #pragma unroll 1
    for (int t = 0; t < NT; ++t) {
        // prefetch next tile's x-halo into registers (latency hides under compute)
        int bn, h0n, w0n;
        if (t + 1 < NT) {
            tile_coords(blockIdx.x + (t + 1) * NBLK, bn, h0n, w0n);
            xload_regs(x, bn, h0n, w0n, v0, v1);
        }

        // ---- compute current tile ----
        const int base0 = q * XSZ + wave * XW + m;
        half2 pd0[13], pd1[13], pd2[13], pd3[13];
        patch_from_lds(xt, base0,      pd0);
        patch_from_lds(xt, base0 + 16, pd1);
        patch_from_lds(xt, base0 + 32, pd2);
        patch_from_lds(xt, base0 + 48, pd3);

        floatx4 acc0 = {bo, bo, bo, bo};
        floatx4 acc1 = acc0, acc2 = acc0, acc3 = acc0;
        gemm_all(pd0, pd1, pd2, pd3, sB + lane * 8,
                 acc0, acc1, acc2, acc3, std::make_index_sequence<NCHUNK>{});

        const int h = h0 + wave;
        if (h < HH) {
            const int rowbase = (b * HH + h) * WW;
            #pragma unroll
            for (int r = 0; r < 4; ++r) {
                const int wA = w0 + q * 4 + r;
                if (wA < WW) out[(rowbase + wA) * NF + m] = acc0[r];
                const int wB = w0 + 16 + q * 4 + r;
                if (wB < WW) out[(rowbase + wB) * NF + m] = acc1[r];
                const int wC = w0 + 32 + q * 4 + r;
                if (wC < WW) out[(rowbase + wC) * NF + m] = acc2[r];
                const int wD = w0 + 48 + q * 4 + r;
                if (wD < WW) out[(rowbase + wD) * NF + m] = acc3[r];
            }
        }

        // ---- swap in next tile's x (cheap: regs->LDS + barriers) ----
        if (t + 1 < NT) {
            b = bn; h0 = h0n; w0 = w0n;
            __syncthreads();              // everyone done reading xt
            xwrite_lds(xt, v0, v1);
            __syncthreads();              // writes visible
        }
    }
}

extern "C" void kernel_launch(void* const* d_in, const int* in_sizes, int n_in,
                              void* d_out, int out_size, void* d_ws, size_t ws_size,
                              hipStream_t stream) {
    const float* x      = (const float*)d_in[0];
    const float* lin_w  = (const float*)d_in[1];
    const float* quad_w = (const float*)d_in[2];
    const float* bias   = (const float*)d_in[3];
    float* out = (float*)d_out;
    _Float16* fragB = (_Float16*)d_ws;   // 50,176 B

    prep_frags<<<dim3(NCHUNK), dim3(64), 0, stream>>>(lin_w, quad_w, fragB);

    convquad_gemm<<<dim3(NBLK), dim3(512), 0, stream>>>(x, bias, fragB, out);
}

// Round 13
// 101.551 us; speedup vs baseline: 1.0236x; 1.0084x over previous
//
#include <hip/hip_runtime.h>
#include <utility>

// ConvQuad2D as ONE pure GEMM over packed-f16 pair-features.
// r12 post-mortem: B-path/persistence/occupancy all neutral -> main kernel
// (~37us) runs at ~the un-overlapped sum of pipes: MFMA 12 + VALU 9 + DS 15.
// Binding per-pixel invariants: patch ds_read_b32 traffic + MFMA/VALU floor.
// r13: vertical tap reuse — wave = 2 adjacent rows x 2 col-groups (tile
// 32x16): lane loads a 6x5 tap window (30 b32) per col-group serving BOTH
// rows' 5x5 patches -> patch DS 100->60 b32/wave (DS/CU ~16 -> ~12us).
// Keeps r12: persistent 512 blocks, B staged once to LDS, x-halo register
// prefetch for tile t+1.
// Feature order (prep owns matching weights): slot s in [0,196):
//   s<181: pair (i,g), g in [i>>1,12]: (p_i*p_{2g}, p_i*p_{2g+1});
//          weights: j==i -> Wq[d,i,i]; j>i -> Wq[d,i,j]+Wq[d,j,i]; else 0
//   s<194: linear t=s-181: (p_{2t},p_{2t+1}) w/ Klin[j,d,o] (j==25 -> 0); else pad.
// k-slot: chunk c=s>>2, lane q = channel d, e = feature-in-chunk.

typedef _Float16 half2 __attribute__((ext_vector_type(2)));
typedef _Float16 half4 __attribute__((ext_vector_type(4)));
typedef _Float16 half8 __attribute__((ext_vector_type(8)));
typedef float floatx4 __attribute__((ext_vector_type(4)));

#define BB 8
#define HH 250
#define WW 250
#define NF 16
#define NSLOT_PAIR 181
#define NSLOT_LIN  13
#define NCHUNK     49              // 49*4 = 196 half2 slots = 392 features/channel
#define NFRAG      (NCHUNK * 64)   // 3136 B-fragments = 50,176 B

#define TW 32                 // tile width  (pixels) = 2 col-groups of 16
#define TH 16                 // tile height = 8 waves x 2 rows
#define XW (TW + 4)           // 36 staged cols
#define XH (TH + 4)           // 20 staged rows
#define XSZ (XW * XH)         // 720 positions

#define NBLK     512          // persistent blocks (2/CU)
#define NTILE_W  8            // ceil(250/32)
#define NTILE_H  16           // ceil(250/16)
#define NTILES   (BB * NTILE_H * NTILE_W)   // 1024
#define NT       (NTILES / NBLK)            // 2 tiles per block

__host__ __device__ constexpr int slot_i(int s) {
    int i = 0, base = 0;
    while (base + (13 - (i >> 1)) <= s) { base += 13 - (i >> 1); ++i; }
    return i;
}
__host__ __device__ constexpr int slot_g(int s) {
    int i = 0, base = 0;
    while (base + (13 - (i >> 1)) <= s) { base += 13 - (i >> 1); ++i; }
    return (i >> 1) + (s - base);
}

// ---------- pre-pass: B fragments in MFMA lane order ----------
__global__ void prep_frags(const float* __restrict__ lin_w,   // (5,5,4,16)
                           const float* __restrict__ quad_w,  // (4,25,25,16)
                           _Float16* __restrict__ fragB) {
    const int c = blockIdx.x;       // 0..48
    const int lane = threadIdx.x;   // 0..63
    const int n = lane & 15;
    const int d = lane >> 4;
    half8 frag;
    #pragma unroll
    for (int e = 0; e < 8; ++e) {
        const int f = c * 8 + e;
        const int s = f >> 1, hf = f & 1;
        float v = 0.f;
        if (s < NSLOT_PAIR) {
            int i = 0, base = 0;
            while (base + (13 - (i >> 1)) <= s) { base += 13 - (i >> 1); ++i; }
            const int g = (i >> 1) + (s - base);
            const int j = 2 * g + hf;
            if (j == i)
                v = quad_w[((d * 25 + i) * 25 + i) * 16 + n];
            else if (j > i && j < 25)
                v = quad_w[((d * 25 + i) * 25 + j) * 16 + n]
                  + quad_w[((d * 25 + j) * 25 + i) * 16 + n];
        } else if (s < NSLOT_PAIR + NSLOT_LIN) {
            const int j = 2 * (s - NSLOT_PAIR) + hf;
            if (j < 25) v = lin_w[(j * 4 + d) * 16 + n];
        }
        frag[e] = (_Float16)v;
    }
    *(half8*)(fragB + (c * 64 + lane) * 8) = frag;
}

// ---------- packed helpers ----------
__device__ __forceinline__ half2 pk(float lo, float hi) {
    return __builtin_bit_cast(half2, __builtin_amdgcn_cvt_pkrtz(lo, hi));
}

template<int S>
__device__ __forceinline__ half2 slotval(const half2 (&pd2)[13]) {
    if constexpr (S < NSLOT_PAIR) {
        constexpr int i = slot_i(S), g = slot_g(S);
        constexpr int ir = i >> 1, ih = i & 1;
        const half2 src = pd2[ir];
        const half2 bi = {src[ih], src[ih]};   // op_sel broadcast
        return bi * pd2[g];                    // v_pk_mul_f16
    } else if constexpr (S < NSLOT_PAIR + NSLOT_LIN) {
        return pd2[S - NSLOT_PAIR];
    } else {
        return half2{(_Float16)0.f, (_Float16)0.f};
    }
}

template<int C>
__device__ __forceinline__ half8 make_frag(const half2 (&pd2)[13]) {
    const half2 a0 = slotval<C * 4 + 0>(pd2);
    const half2 a1 = slotval<C * 4 + 1>(pd2);
    const half2 a2 = slotval<C * 4 + 2>(pd2);
    const half2 a3 = slotval<C * 4 + 3>(pd2);
    const half4 lo = __builtin_shufflevector(a0, a1, 0, 1, 2, 3);
    const half4 hi = __builtin_shufflevector(a2, a3, 0, 1, 2, 3);
    return __builtin_shufflevector(lo, hi, 0, 1, 2, 3, 4, 5, 6, 7);
}

template<size_t... Cs>
__device__ __forceinline__ void gemm_all(
    const half2 (&p0)[13], const half2 (&p1)[13],
    const half2 (&p2)[13], const half2 (&p3)[13],
    const _Float16* sBlane,
    floatx4& a0, floatx4& a1, floatx4& a2, floatx4& a3,
    std::index_sequence<Cs...>) {
    (([&] {
        constexpr int C = (int)Cs;
        const half8 bf = *(const half8*)(sBlane + C * 64 * 8);  // ds_read_b128 imm
        a0 = __builtin_amdgcn_mfma_f32_16x16x32_f16(make_frag<C>(p0), bf, a0, 0, 0, 0);
        a1 = __builtin_amdgcn_mfma_f32_16x16x32_f16(make_frag<C>(p1), bf, a1, 0, 0, 0);
        a2 = __builtin_amdgcn_mfma_f32_16x16x32_f16(make_frag<C>(p2), bf, a2, 0, 0, 0);
        a3 = __builtin_amdgcn_mfma_f32_16x16x32_f16(make_frag<C>(p3), bf, a3, 0, 0, 0);
    }()), ...);
}

// ---------- 6x5 tap window -> two row-patches (vertical reuse) ----------
__device__ __forceinline__ void patches_from_window(const float* xt, int base,
                                                    half2 (&pdT)[13], half2 (&pdB)[13]) {
    float t6[6][5];
    #pragma unroll
    for (int rr = 0; rr < 6; ++rr)
        #pragma unroll
        for (int cc = 0; cc < 5; ++cc)
            t6[rr][cc] = xt[base + rr * XW + cc];

    float pf0[26], pf1[26];
    pf0[25] = 0.f; pf1[25] = 0.f;
    #pragma unroll
    for (int rr = 0; rr < 5; ++rr)
        #pragma unroll
        for (int cc = 0; cc < 5; ++cc) {
            pf0[rr * 5 + cc] = t6[rr][cc];       // pixel at row r0
            pf1[rr * 5 + cc] = t6[rr + 1][cc];   // pixel at row r0+1
        }
    #pragma unroll
    for (int t = 0; t < 13; ++t) {
        pdT[t] = pk(pf0[2 * t], pf0[2 * t + 1]);
        pdB[t] = pk(pf1[2 * t], pf1[2 * t + 1]);
    }
}

// ---------- tile index -> (b, h0, w0) ----------
__device__ __forceinline__ void tile_coords(int T, int& b, int& h0, int& w0) {
    b = T >> 7;                  // 128 tiles per batch image (8w x 16h)
    const int rem = T & 127;
    h0 = (rem >> 3) * TH;
    w0 = (rem & 7) * TW;
}

// ---------- x-halo prefetch into registers (2 positions/thread) ----------
__device__ __forceinline__ void xload_regs(const float* __restrict__ x,
                                           int b, int h0, int w0,
                                           float4& v0, float4& v1) {
    const int p0 = threadIdx.x;
    {
        const int hh = p0 / XW, ww = p0 % XW;
        const int r = h0 + hh - 2, c = w0 + ww - 2;
        v0 = make_float4(0.f, 0.f, 0.f, 0.f);
        if (p0 < XSZ && (unsigned)r < (unsigned)HH && (unsigned)c < (unsigned)WW)
            v0 = ((const float4*)x)[(b * HH + r) * WW + c];
    }
    const int p1 = p0 + 512;
    v1 = make_float4(0.f, 0.f, 0.f, 0.f);
    if (p1 < XSZ) {
        const int hh = p1 / XW, ww = p1 % XW;
        const int r = h0 + hh - 2, c = w0 + ww - 2;
        if ((unsigned)r < (unsigned)HH && (unsigned)c < (unsigned)WW)
            v1 = ((const float4*)x)[(b * HH + r) * WW + c];
    }
}

__device__ __forceinline__ void xwrite_lds(float* xt, const float4& v0, const float4& v1) {
    const int p0 = threadIdx.x;
    if (p0 < XSZ) {
        xt[0 * XSZ + p0] = v0.x;
        xt[1 * XSZ + p0] = v0.y;
        xt[2 * XSZ + p0] = v0.z;
        xt[3 * XSZ + p0] = v0.w;
    }
    const int p1 = p0 + 512;
    if (p1 < XSZ) {
        xt[0 * XSZ + p1] = v1.x;
        xt[1 * XSZ + p1] = v1.y;
        xt[2 * XSZ + p1] = v1.z;
        xt[3 * XSZ + p1] = v1.w;
    }
}

// ---------- main kernel: 512 persistent threads, 2 tiles per block ----------
// wave = 2 adjacent rows x 32 cols; segments: (r0,c0-15),(r0,c16-31),(r1,c0-15),(r1,c16-31)
__global__ __launch_bounds__(512, 4) void convquad_gemm(
    const float* __restrict__ x,       // (8,250,250,4)
    const float* __restrict__ bias,    // (16,)
    const _Float16* __restrict__ fragB,
    float* __restrict__ out)           // (8,250,250,16)
{
    __shared__ float xt[4 * XSZ];                     // 11,520 B: [c][hh][ww]
    __shared__ __align__(16) _Float16 sB[NFRAG * 8];  // 50,176 B

    const int lane = threadIdx.x & 63;
    const int wv = threadIdx.x >> 6;     // row-pair within tile
    const int m = lane & 15;             // pixel within 16-col segment; also o
    const int q = lane >> 4;             // channel for A; row-quad for D
    const float bo = bias[m];

    // ---- prologue: prefetch x (tile 0) + copy B, one barrier ----
    int b, h0, w0;
    tile_coords(blockIdx.x, b, h0, w0);
    float4 v0, v1;
    xload_regs(x, b, h0, w0, v0, v1);

    {   // coalesced 50KB B copy: global (L2-hot) -> LDS
        const float4* src = (const float4*)fragB;
        float4* dst = (float4*)sB;
        #pragma unroll
        for (int t = threadIdx.x; t < NFRAG * 8 / 8; t += 512) dst[t] = src[t];
    }
    xwrite_lds(xt, v0, v1);
    __syncthreads();

    #pragma unroll 1
    for (int t = 0; t < NT; ++t) {
        // prefetch next tile's x-halo into registers (latency hides under compute)
        int bn, h0n, w0n;
        if (t + 1 < NT) {
            tile_coords(blockIdx.x + (t + 1) * NBLK, bn, h0n, w0n);
            xload_regs(x, bn, h0n, w0n, v0, v1);
        }

        // ---- patches: 6x5 window per col-group serves both rows ----
        const int base = q * XSZ + (2 * wv) * XW + m;
        half2 pd0[13], pd1[13], pd2[13], pd3[13];
        patches_from_window(xt, base,      pd0, pd2);   // col-group 0: rows r0, r1
        patches_from_window(xt, base + 16, pd1, pd3);   // col-group 1: rows r0, r1

        floatx4 acc0 = {bo, bo, bo, bo};
        floatx4 acc1 = acc0, acc2 = acc0, acc3 = acc0;
        gemm_all(pd0, pd1, pd2, pd3, sB + lane * 8,
                 acc0, acc1, acc2, acc3, std::make_index_sequence<NCHUNK>{});

        // ---- store: seg0/1 -> row r0, seg2/3 -> row r1 ----
        const int r0 = h0 + 2 * wv;
        #pragma unroll
        for (int rr = 0; rr < 2; ++rr) {
            const int h = r0 + rr;
            if (h < HH) {
                const int rowbase = (b * HH + h) * WW;
                const floatx4& aA = rr ? acc2 : acc0;
                const floatx4& aB = rr ? acc3 : acc1;
                #pragma unroll
                for (int r = 0; r < 4; ++r) {
                    const int wA = w0 + q * 4 + r;
                    if (wA < WW) out[(rowbase + wA) * NF + m] = aA[r];
                    const int wB = w0 + 16 + q * 4 + r;
                    if (wB < WW) out[(rowbase + wB) * NF + m] = aB[r];
                }
            }
        }

        // ---- swap in next tile's x (cheap: regs->LDS + barriers) ----
        if (t + 1 < NT) {
            b = bn; h0 = h0n; w0 = w0n;
            __syncthreads();              // everyone done reading xt
            xwrite_lds(xt, v0, v1);
            __syncthreads();              // writes visible
        }
    }
}

extern "C" void kernel_launch(void* const* d_in, const int* in_sizes, int n_in,
                              void* d_out, int out_size, void* d_ws, size_t ws_size,
                              hipStream_t stream) {
    const float* x      = (const float*)d_in[0];
    const float* lin_w  = (const float*)d_in[1];
    const float* quad_w = (const float*)d_in[2];
    const float* bias   = (const float*)d_in[3];
    float* out = (float*)d_out;
    _Float16* fragB = (_Float16*)d_ws;   // 50,176 B

    prep_frags<<<dim3(NCHUNK), dim3(64), 0, stream>>>(lin_w, quad_w, fragB);

    convquad_gemm<<<dim3(NBLK), dim3(512), 0, stream>>>(x, bias, fragB, out);
}